// Round 2
// baseline (1421.726 us; speedup 1.0000x reference)
//
#include <hip/hip_runtime.h>
#include <cstdint>
#include <cstddef>

#define NN 50000   // nodes
#define NE 400000  // edges
#define NG 10000   // pharmacophore groups
#define NBG 256    // graphs

static inline int imin(int a, int b) { return a < b ? a : b; }

__device__ __forceinline__ float wave_sum64(float v) {
#pragma unroll
  for (int off = 32; off > 0; off >>= 1) v += __shfl_xor(v, off, 64);
  return v;
}

__device__ __forceinline__ float bcast_lane(float v, int k) {
  return __int_as_float(__builtin_amdgcn_readlane(__float_as_int(v), k));
}

// ---------------- CSR build ----------------

__global__ void count_dst_kernel(const int* __restrict__ dst, int* __restrict__ cnt, int E) {
  int e = blockIdx.x * blockDim.x + threadIdx.x;
  if (e < E) atomicAdd(&cnt[dst[e]], 1);
}

__global__ void fill_node_kernel(const int* __restrict__ src, const int* __restrict__ dst,
                                 int* __restrict__ cursor, int* __restrict__ csr_src,
                                 int* __restrict__ csr_eid, int E) {
  int e = blockIdx.x * blockDim.x + threadIdx.x;
  if (e < E) {
    int pos = atomicAdd(&cursor[dst[e]], 1);
    csr_src[pos] = src[e];
    csr_eid[pos] = e;
  }
}

__global__ void count_grp_kernel(const int* __restrict__ src, const int* __restrict__ dst,
                                 const int* __restrict__ ph, int* __restrict__ cnt, int E) {
  int e = blockIdx.x * blockDim.x + threadIdx.x;
  if (e < E) {
    int sg = ph[src[e]], dg = ph[dst[e]];
    if (sg != dg) atomicAdd(&cnt[dg], 1);
  }
}

__global__ void fill_grp_kernel(const int* __restrict__ src, const int* __restrict__ dst,
                                const int* __restrict__ ph, int* __restrict__ cursor,
                                int* __restrict__ gsrc, int E) {
  int e = blockIdx.x * blockDim.x + threadIdx.x;
  if (e < E) {
    int sg = ph[src[e]], dg = ph[dst[e]];
    if (sg != dg) {
      int pos = atomicAdd(&cursor[dg], 1);
      gsrc[pos] = sg;
    }
  }
}

// Single-block exclusive scan (n up to ~50k). rowptr gets n+1 entries.
__global__ void exscan_block_kernel(const int* __restrict__ cnt, int* __restrict__ rowptr, int n) {
  __shared__ int wsum[16];
  int tid = threadIdx.x;
  int chunk = (n + 1023) >> 10;
  int s0 = tid * chunk;
  int s1 = s0 + chunk; if (s1 > n) s1 = n;
  int sum = 0;
  for (int i = s0; i < s1; i++) sum += cnt[i];
  int lane = tid & 63, w = tid >> 6;
  int v = sum, s = sum;
#pragma unroll
  for (int off = 1; off < 64; off <<= 1) {
    int t = __shfl_up(s, off);
    if (lane >= off) s += t;
  }
  if (lane == 63) wsum[w] = s;
  __syncthreads();
  if (tid == 0) {
    int c = 0;
#pragma unroll
    for (int i = 0; i < 16; i++) { int t = wsum[i]; wsum[i] = c; c += t; }
  }
  __syncthreads();
  int run = wsum[w] + (s - v);  // exclusive prefix for this thread's chunk
  for (int i = s0; i < s1; i++) { rowptr[i] = run; run += cnt[i]; }
  if (tid == 1023) rowptr[n] = run;
}

// ---------------- edge-attr helpers ----------------

// mean of raw 16-dim edge_attr over incoming edges per node (0 if deg==0)
__global__ void mean_attr_kernel(const int* __restrict__ rowptr, const int* __restrict__ csr_eid,
                                 const float* __restrict__ eattr, float* __restrict__ mattr, int N) {
  int t = blockIdx.x * blockDim.x + threadIdx.x;
  if (t >= N * 16) return;
  int n = t >> 4, k = t & 15;
  int e0 = rowptr[n], e1 = rowptr[n + 1];
  float s = 0.f;
  for (int p = e0; p < e1; p++) s += eattr[(size_t)csr_eid[p] * 16 + k];
  mattr[t] = (e1 > e0) ? s / (float)(e1 - e0) : 0.f;
}

// Fused We2 = w_edge @ g_we  (16xF),  be2 = b_edge @ g_we (F), for layers 1 and 2.
__global__ void fuse_we_kernel(const float* __restrict__ w_edge, const float* __restrict__ b_edge,
                               const float* __restrict__ g1_we, const float* __restrict__ g2_we,
                               float* __restrict__ We2_1, float* __restrict__ be2_1,
                               float* __restrict__ We2_2, float* __restrict__ be2_2) {
  int t = blockIdx.x * blockDim.x + threadIdx.x;
  if (t < 16 * 256) {
    int k = t >> 8, j = t & 255;
    float s = 0.f;
    for (int c = 0; c < 64; c++) s += w_edge[k * 64 + c] * g1_we[c * 256 + j];
    We2_1[t] = s;
  } else if (t < 16 * 256 + 256) {
    int j = t - 16 * 256;
    float s = 0.f;
    for (int c = 0; c < 64; c++) s += b_edge[c] * g1_we[c * 256 + j];
    be2_1[j] = s;
  } else if (t < 16 * 256 + 256 + 16 * 64) {
    int u = t - (16 * 256 + 256);
    int k = u >> 6, j = u & 63;
    float s = 0.f;
    for (int c = 0; c < 64; c++) s += w_edge[k * 64 + c] * g2_we[c * 64 + j];
    We2_2[u] = s;
  } else if (t < 16 * 256 + 256 + 16 * 64 + 64) {
    int j = t - (16 * 256 + 256 + 16 * 64);
    float s = 0.f;
    for (int c = 0; c < 64; c++) s += b_edge[c] * g2_we[c * 64 + j];
    be2_2[j] = s;
  }
}

// ---------------- dense transform: Y[r,:] = X[r,:] @ W ----------------
// lane owns one row; W rows are wave-uniform (scalar loads); grid.y tiles OUT.
template <int IN, int OUT>
__global__ __launch_bounds__(256) void matvec_kernel(int nRows,
    const float* __restrict__ X, const float* __restrict__ W, float* __restrict__ Y) {
  constexpr int KT = IN / 64;
  const int lane = threadIdx.x & 63;
  const int wv = threadIdx.x >> 6;
  const int batch = blockIdx.x * 4 + wv;
  const int jc = blockIdx.y;
  const int row = batch * 64 + lane;
  const int rc = row < nRows ? row : nRows - 1;
  const float* xp = X + (size_t)rc * IN;
  float acc[64];
#pragma unroll
  for (int j = 0; j < 64; j++) acc[j] = 0.f;
  for (int kt = 0; kt < KT; kt++) {
    float xr[64];
#pragma unroll
    for (int q = 0; q < 16; q++) {
      const float4 v = *(const float4*)(xp + kt * 64 + q * 4);
      xr[q * 4 + 0] = v.x; xr[q * 4 + 1] = v.y; xr[q * 4 + 2] = v.z; xr[q * 4 + 3] = v.w;
    }
    const float* wb = W + (size_t)kt * 64 * OUT + jc * 64;
#pragma unroll
    for (int k = 0; k < 64; k++) {
#pragma unroll
      for (int j = 0; j < 64; j++) acc[j] += xr[k] * wb[(size_t)k * OUT + j];
    }
  }
  if (row < nRows) {
    float* yp = Y + (size_t)row * OUT + jc * 64;
#pragma unroll
    for (int q = 0; q < 16; q++) {
      float4 v;
      v.x = acc[q * 4 + 0]; v.y = acc[q * 4 + 1]; v.z = acc[q * 4 + 2]; v.w = acc[q * 4 + 3];
      *(float4*)(yp + q * 4) = v;
    }
  }
}

// ---------------- fused GATv2 layer: one wave per dst node, online softmax ----------------
template <int H, bool HASE>
__global__ __launch_bounds__(256) void gat_kernel(
    int N,
    const int* __restrict__ rowptr,
    const int* __restrict__ csr_src,
    const int* __restrict__ csr_eid,
    const float* __restrict__ eattr,   // E x 16 raw edge attrs
    const float* __restrict__ mattr,   // N x 16 mean raw attrs (self-loop)
    const float* __restrict__ We2,     // 16 x F fused
    const float* __restrict__ be2,     // F fused bias
    const float* __restrict__ xl,      // N x F
    const float* __restrict__ xr,      // N x F
    const float* __restrict__ att,     // H x 64
    const float* __restrict__ bias,    // F
    float* __restrict__ out)           // N x F  (ELU applied)
{
  constexpr int F = H * 64;
  const int lane = threadIdx.x & 63;
  const int wv = threadIdx.x >> 6;

  float att_r[H], bias_r[H], be2_r[H], wreg[16 * H];
#pragma unroll
  for (int r = 0; r < H; r++) {
    att_r[r] = att[r * 64 + lane];
    bias_r[r] = bias[r * 64 + lane];
    be2_r[r] = 0.f;
  }
  if constexpr (HASE) {
#pragma unroll
    for (int r = 0; r < H; r++) be2_r[r] = be2[r * 64 + lane];
#pragma unroll
    for (int k = 0; k < 16; k++)
#pragma unroll
      for (int r = 0; r < H; r++) wreg[k * H + r] = We2[k * F + r * 64 + lane];
  }

  for (int n = blockIdx.x * 4 + wv; n < N; n += gridDim.x * 4) {
    const int e0 = rowptr[n], e1 = rowptr[n + 1];
    float xr_r[H], xls[H];
#pragma unroll
    for (int r = 0; r < H; r++) {
      xr_r[r] = xr[(size_t)n * F + r * 64 + lane];
      xls[r] = xl[(size_t)n * F + r * 64 + lane];
    }
    // self-loop edge feature: mean of incoming ea (0 vector if deg==0)
    float ev[H];
#pragma unroll
    for (int r = 0; r < H; r++) ev[r] = 0.f;
    if constexpr (HASE) {
      if (e1 > e0) {
        float av = (lane < 16) ? mattr[(size_t)n * 16 + lane] : 0.f;
#pragma unroll
        for (int k = 0; k < 16; k++) {
          float a = bcast_lane(av, k);
#pragma unroll
          for (int r = 0; r < H; r++) ev[r] += a * wreg[k * H + r];
        }
#pragma unroll
        for (int r = 0; r < H; r++) ev[r] += be2_r[r];
      }
    }
    // init online-softmax state with the self-loop
    float m_run[H], den[H], acc[H];
#pragma unroll
    for (int r = 0; r < H; r++) {
      float vv = xls[r] + xr_r[r] + ev[r];
      vv = vv > 0.f ? vv : 0.2f * vv;
      float sc = wave_sum64(vv * att_r[r]);
      m_run[r] = sc; den[r] = 1.f; acc[r] = xls[r];
    }
    // incoming edges
    for (int pos = e0; pos < e1; pos++) {
      const int s = csr_src[pos];
      float ev2[H];
#pragma unroll
      for (int r = 0; r < H; r++) ev2[r] = 0.f;
      if constexpr (HASE) {
        const int eid = csr_eid[pos];
        float av = (lane < 16) ? eattr[(size_t)eid * 16 + lane] : 0.f;
#pragma unroll
        for (int k = 0; k < 16; k++) {
          float a = bcast_lane(av, k);
#pragma unroll
          for (int r = 0; r < H; r++) ev2[r] += a * wreg[k * H + r];
        }
#pragma unroll
        for (int r = 0; r < H; r++) ev2[r] += be2_r[r];
      }
      float xsr[H], sc[H];
#pragma unroll
      for (int r = 0; r < H; r++) xsr[r] = xl[(size_t)s * F + r * 64 + lane];
#pragma unroll
      for (int r = 0; r < H; r++) {
        float vv = xsr[r] + xr_r[r] + ev2[r];
        vv = vv > 0.f ? vv : 0.2f * vv;
        sc[r] = wave_sum64(vv * att_r[r]);
      }
#pragma unroll
      for (int r = 0; r < H; r++) {
        float mo = m_run[r];
        float mn = fmaxf(mo, sc[r]);
        float sa = __expf(mo - mn);
        float ex = __expf(sc[r] - mn);
        den[r] = den[r] * sa + ex;
        acc[r] = acc[r] * sa + ex * xsr[r];
        m_run[r] = mn;
      }
    }
#pragma unroll
    for (int r = 0; r < H; r++) {
      float o = acc[r] / den[r] + bias_r[r];
      out[(size_t)n * F + r * 64 + lane] = o > 0.f ? o : (__expf(o) - 1.f);
    }
  }
}

// ---------------- pooling ----------------

__global__ void pool_ph_scatter_kernel(const float* __restrict__ h, const int* __restrict__ ph,
                                       const int* __restrict__ batch, float* __restrict__ gsum,
                                       float* __restrict__ bsum, int* __restrict__ gcnt, int N) {
  int t = blockIdx.x * blockDim.x + threadIdx.x;
  if (t >= N * 64) return;
  int n = t >> 6, c = t & 63;
  int g = ph[n];
  atomicAdd(&gsum[(size_t)g * 64 + c], h[t]);
  if (c == 0) {
    atomicAdd(&gcnt[g], 1);
    atomicAdd(&bsum[g], (float)batch[n]);
  }
}

__global__ void pool_ph_final_kernel(const float* __restrict__ gsum, const float* __restrict__ bsum,
                                     const int* __restrict__ gcnt, float* __restrict__ gx,
                                     int* __restrict__ rbatch, int G) {
  int t = blockIdx.x * blockDim.x + threadIdx.x;
  if (t >= G * 64) return;
  int g = t >> 6, c = t & 63;
  float cn = fmaxf((float)gcnt[g], 1.f);
  gx[t] = gsum[t] / cn;
  if (c == 0) rbatch[g] = (int)(bsum[g] / cn);
}

__global__ void pool_graph_scatter_kernel(const float* __restrict__ h, const int* __restrict__ rbatch,
                                          float* __restrict__ psum, int* __restrict__ pcnt, int G) {
  int t = blockIdx.x * blockDim.x + threadIdx.x;
  if (t >= G * 64) return;
  int g = t >> 6, c = t & 63;
  int b = rbatch[g];
  atomicAdd(&psum[(size_t)b * 64 + c], h[t]);
  if (c == 0) atomicAdd(&pcnt[b], 1);
}

__global__ void pool_graph_final_kernel(const float* __restrict__ psum, const int* __restrict__ pcnt,
                                        float* __restrict__ pooled) {
  int t = blockIdx.x * blockDim.x + threadIdx.x;
  if (t >= NBG * 64) return;
  int b = t >> 6;
  pooled[t] = psum[t] / fmaxf((float)pcnt[b], 1.f);
}

// ---------------- final MLP ----------------

__global__ void fc1_kernel(const float* __restrict__ pooled, const float* __restrict__ w1,
                           const float* __restrict__ b1, float* __restrict__ o) {
  int g = blockIdx.x, lane = threadIdx.x;  // blockDim = 64
  float p = pooled[g * 64 + lane];
  float acc = b1[lane];
#pragma unroll 8
  for (int k = 0; k < 64; k++) acc += __shfl(p, k, 64) * w1[k * 64 + lane];
  o[g * 64 + lane] = fmaxf(acc, 0.f);
}

__global__ void fc2_kernel(const float* __restrict__ o1, const float* __restrict__ w2,
                           const float* __restrict__ b2, float* __restrict__ out) {
  int g = threadIdx.x;  // 256 threads
  float acc = b2[0];
  for (int k = 0; k < 64; k++) acc += o1[g * 64 + k] * w2[k];
  out[g] = acc;
}

// ---------------- launch ----------------

extern "C" void kernel_launch(void* const* d_in, const int* in_sizes, int n_in,
                              void* d_out, int out_size, void* d_ws, size_t ws_size,
                              hipStream_t stream) {
  (void)in_sizes; (void)n_in; (void)out_size; (void)ws_size;
  const float* x      = (const float*)d_in[0];
  const int*   eidx   = (const int*)d_in[1];
  const float* eattr  = (const float*)d_in[2];
  const int*   batch  = (const int*)d_in[3];
  const int*   ph     = (const int*)d_in[4];
  const float* w_edge = (const float*)d_in[6];
  const float* b_edge = (const float*)d_in[7];
  const float* g1_wl  = (const float*)d_in[8];
  const float* g1_wr  = (const float*)d_in[9];
  const float* g1_att = (const float*)d_in[10];
  const float* g1_we  = (const float*)d_in[11];
  const float* g1_b   = (const float*)d_in[12];
  const float* g2_wl  = (const float*)d_in[13];
  const float* g2_wr  = (const float*)d_in[14];
  const float* g2_att = (const float*)d_in[15];
  const float* g2_we  = (const float*)d_in[16];
  const float* g2_b   = (const float*)d_in[17];
  const float* g3_wl  = (const float*)d_in[18];
  const float* g3_wr  = (const float*)d_in[19];
  const float* g3_att = (const float*)d_in[20];
  const float* g3_b   = (const float*)d_in[21];
  const float* g4_wl  = (const float*)d_in[22];
  const float* g4_wr  = (const float*)d_in[23];
  const float* g4_att = (const float*)d_in[24];
  const float* g4_b   = (const float*)d_in[25];
  const float* w1     = (const float*)d_in[26];
  const float* b1     = (const float*)d_in[27];
  const float* w2     = (const float*)d_in[28];
  const float* b2     = (const float*)d_in[29];
  float* out = (float*)d_out;
  const int* src = eidx;
  const int* dst = eidx + NE;

  char* ws = (char*)d_ws;
  size_t off = 0;
  auto alloc = [&](size_t bytes) -> void* {
    size_t o = off;
    off = (off + bytes + 255) & ~(size_t)255;
    return (void*)(ws + o);
  };
  int*   rowptr  = (int*)alloc((NN + 1) * 4);
  int*   cursor  = (int*)alloc((NN + 1) * 4);
  int*   csr_src = (int*)alloc((size_t)NE * 4);
  int*   csr_eid = (int*)alloc((size_t)NE * 4);
  int*   growptr = (int*)alloc((NG + 1) * 4);
  int*   gcursor = (int*)alloc((NG + 1) * 4);
  int*   gsrc    = (int*)alloc((size_t)NE * 4);
  float* mattr   = (float*)alloc((size_t)NN * 16 * 4);
  float* We2_1   = (float*)alloc(16 * 256 * 4);
  float* be2_1   = (float*)alloc(256 * 4);
  float* We2_2   = (float*)alloc(16 * 64 * 4);
  float* be2_2   = (float*)alloc(64 * 4);
  float* xl1     = (float*)alloc((size_t)NN * 256 * 4);
  float* xr1     = (float*)alloc((size_t)NN * 256 * 4);
  float* h1      = (float*)alloc((size_t)NN * 256 * 4);
  float* bsum    = (float*)alloc(NG * 4);
  int*   gcnt    = (int*)alloc(NG * 4);
  int*   rbatch  = (int*)alloc(NG * 4);
  float* psum    = (float*)alloc(NBG * 64 * 4);
  int*   pcnt    = (int*)alloc(NBG * 4);
  float* pooled  = (float*)alloc(NBG * 64 * 4);
  float* fc1o    = (float*)alloc(NBG * 64 * 4);
  // region reuse: xl1 region hosts layer-2 buffers (xl1/xr1 dead after gat1)
  float* xl2 = xl1;
  float* xr2 = xl1 + (size_t)NN * 64;
  float* h2  = xl1 + (size_t)NN * 128;
  // xr1 region hosts group-level buffers (dead after gat1)
  float* gsum = xr1;
  float* gx   = xr1 + (size_t)NG * 64 * 1;
  float* xl3  = xr1 + (size_t)NG * 64 * 2;
  float* xr3  = xr1 + (size_t)NG * 64 * 3;
  float* h3   = xr1 + (size_t)NG * 64 * 4;
  float* xl4  = xr1 + (size_t)NG * 64 * 5;
  float* xr4  = xr1 + (size_t)NG * 64 * 6;
  float* h4   = xr1 + (size_t)NG * 64 * 7;

  // ---- node CSR ----
  hipMemsetAsync(cursor, 0, (NN + 1) * 4, stream);
  count_dst_kernel<<<(NE + 255) / 256, 256, 0, stream>>>(dst, cursor, NE);
  exscan_block_kernel<<<1, 1024, 0, stream>>>(cursor, rowptr, NN);
  hipMemcpyAsync(cursor, rowptr, (NN + 1) * 4, hipMemcpyDeviceToDevice, stream);
  fill_node_kernel<<<(NE + 255) / 256, 256, 0, stream>>>(src, dst, cursor, csr_src, csr_eid, NE);
  mean_attr_kernel<<<(NN * 16 + 255) / 256, 256, 0, stream>>>(rowptr, csr_eid, eattr, mattr, NN);
  fuse_we_kernel<<<(16 * 256 + 256 + 16 * 64 + 64 + 255) / 256, 256, 0, stream>>>(
      w_edge, b_edge, g1_we, g2_we, We2_1, be2_1, We2_2, be2_2);

  // ---- layer 1 ----
  {
    dim3 g1((NN + 255) / 256, 4);
    matvec_kernel<64, 256><<<g1, 256, 0, stream>>>(NN, x, g1_wl, xl1);
    matvec_kernel<64, 256><<<g1, 256, 0, stream>>>(NN, x, g1_wr, xr1);
  }
  int gatgrid = imin((NN + 3) / 4, 3072);
  gat_kernel<4, true><<<gatgrid, 256, 0, stream>>>(NN, rowptr, csr_src, csr_eid, eattr, mattr,
                                                   We2_1, be2_1, xl1, xr1, g1_att, g1_b, h1);
  // ---- layer 2 ----
  {
    dim3 g2((NN + 255) / 256, 1);
    matvec_kernel<256, 64><<<g2, 256, 0, stream>>>(NN, h1, g2_wl, xl2);
    matvec_kernel<256, 64><<<g2, 256, 0, stream>>>(NN, h1, g2_wr, xr2);
  }
  gat_kernel<1, true><<<gatgrid, 256, 0, stream>>>(NN, rowptr, csr_src, csr_eid, eattr, mattr,
                                                   We2_2, be2_2, xl2, xr2, g2_att, g2_b, h2);

  // ---- pharmacophore pooling ----
  hipMemsetAsync(gsum, 0, (size_t)NG * 64 * 4, stream);
  hipMemsetAsync(bsum, 0, NG * 4, stream);
  hipMemsetAsync(gcnt, 0, NG * 4, stream);
  pool_ph_scatter_kernel<<<(NN * 64 + 255) / 256, 256, 0, stream>>>(h2, ph, batch, gsum, bsum, gcnt, NN);
  pool_ph_final_kernel<<<(NG * 64 + 255) / 256, 256, 0, stream>>>(gsum, bsum, gcnt, gx, rbatch, NG);

  // ---- group CSR (intra-group edges masked) ----
  hipMemsetAsync(gcursor, 0, (NG + 1) * 4, stream);
  count_grp_kernel<<<(NE + 255) / 256, 256, 0, stream>>>(src, dst, ph, gcursor, NE);
  exscan_block_kernel<<<1, 1024, 0, stream>>>(gcursor, growptr, NG);
  hipMemcpyAsync(gcursor, growptr, (NG + 1) * 4, hipMemcpyDeviceToDevice, stream);
  fill_grp_kernel<<<(NE + 255) / 256, 256, 0, stream>>>(src, dst, ph, gcursor, gsrc, NE);

  // ---- layers 3 & 4 ----
  int gatgrid2 = imin((NG + 3) / 4, 2560);
  {
    dim3 g3((NG + 255) / 256, 1);
    matvec_kernel<64, 64><<<g3, 256, 0, stream>>>(NG, gx, g3_wl, xl3);
    matvec_kernel<64, 64><<<g3, 256, 0, stream>>>(NG, gx, g3_wr, xr3);
    gat_kernel<1, false><<<gatgrid2, 256, 0, stream>>>(NG, growptr, gsrc, nullptr, nullptr, nullptr,
                                                       nullptr, nullptr, xl3, xr3, g3_att, g3_b, h3);
    matvec_kernel<64, 64><<<g3, 256, 0, stream>>>(NG, h3, g4_wl, xl4);
    matvec_kernel<64, 64><<<g3, 256, 0, stream>>>(NG, h3, g4_wr, xr4);
    gat_kernel<1, false><<<gatgrid2, 256, 0, stream>>>(NG, growptr, gsrc, nullptr, nullptr, nullptr,
                                                       nullptr, nullptr, xl4, xr4, g4_att, g4_b, h4);
  }

  // ---- global mean pool + MLP ----
  hipMemsetAsync(psum, 0, NBG * 64 * 4, stream);
  hipMemsetAsync(pcnt, 0, NBG * 4, stream);
  pool_graph_scatter_kernel<<<(NG * 64 + 255) / 256, 256, 0, stream>>>(h4, rbatch, psum, pcnt, NG);
  pool_graph_final_kernel<<<(NBG * 64 + 255) / 256, 256, 0, stream>>>(psum, pcnt, pooled);
  fc1_kernel<<<NBG, 64, 0, stream>>>(pooled, w1, b1, fc1o);
  fc2_kernel<<<1, 256, 0, stream>>>(fc1o, w2, b2, out);
}